// Round 13
// baseline (495.793 us; speedup 1.0000x reference)
//
#include <hip/hip_runtime.h>
#include <math.h>

#define N_NODES 100000
#define N_EDGES 1600000
#define HDIM    256
#define NGRAPH  64

#define SCAN_BLK 1024
#define SCAN_NB  ((N_NODES + SCAN_BLK - 1) / SCAN_BLK)  // 98

#define FB 128  // nodes per fused-gemm block (32/wave x 4 waves)

typedef __attribute__((ext_vector_type(8))) short bf16x8;
typedef __attribute__((ext_vector_type(4))) float f32x4;
typedef __attribute__((ext_vector_type(8))) unsigned short u16x8;

__device__ __forceinline__ ushort f2b(float f) {
    union { float f; unsigned u; } x; x.f = f;
    unsigned u = x.u;
    unsigned r = u + 0x7fffu + ((u >> 16) & 1u);
    return (ushort)(r >> 16);
}
__device__ __forceinline__ float b2f(ushort h) {
    union { unsigned u; float f; } x; x.u = ((unsigned)h) << 16;
    return x.f;
}

// ---------------- CSR build ----------------
__global__ void k_count(const int* __restrict__ ei, int* __restrict__ cnt,
                        int* __restrict__ slot) {
    int t = blockIdx.x * blockDim.x + threadIdx.x;
    int e0 = t * 16;
    if (e0 >= N_EDGES) return;
    int d[16];
#pragma unroll
    for (int j = 0; j < 16; ++j) d[j] = ei[N_EDGES + e0 + j];
    int s[16];
#pragma unroll
    for (int j = 0; j < 16; ++j) s[j] = atomicAdd(&cnt[d[j]], 1);
#pragma unroll
    for (int j = 0; j < 16; ++j) slot[e0 + j] = s[j];
}

__global__ __launch_bounds__(1024) void k_scan1(const int* __restrict__ cnt,
                                                int* __restrict__ rowptr,
                                                int* __restrict__ bsum) {
    __shared__ int lds[SCAN_BLK];
    int t = threadIdx.x;
    int i = blockIdx.x * SCAN_BLK + t;
    int v = (i < N_NODES) ? cnt[i] : 0;
    lds[t] = v;
    __syncthreads();
    for (int off = 1; off < SCAN_BLK; off <<= 1) {
        int u = (t >= off) ? lds[t - off] : 0;
        __syncthreads();
        lds[t] += u;
        __syncthreads();
    }
    if (i < N_NODES) rowptr[i] = lds[t] - v;
    if (t == SCAN_BLK - 1) bsum[blockIdx.x] = lds[t];
}

__global__ __launch_bounds__(128) void k_scan2(int* __restrict__ bsum) {
    __shared__ int lds[128];
    int t = threadIdx.x;
    int v = (t < SCAN_NB) ? bsum[t] : 0;
    lds[t] = v;
    __syncthreads();
    for (int off = 1; off < 128; off <<= 1) {
        int u = (t >= off) ? lds[t - off] : 0;
        __syncthreads();
        lds[t] += u;
        __syncthreads();
    }
    if (t < SCAN_NB) bsum[t] = lds[t] - v;
}

__global__ void k_dinv_fix(const int* __restrict__ cnt, const float* __restrict__ x,
                           const int* __restrict__ bsum,
                           float* __restrict__ dinv, float* __restrict__ xd,
                           int* __restrict__ rowptr) {
    int i = blockIdx.x * blockDim.x + threadIdx.x;
    if (i < N_NODES) {
        rowptr[i] += bsum[i >> 10];
        float d = (float)(cnt[i] + 1);
        float dv = 1.0f / sqrtf(d);
        dinv[i] = dv;
        xd[i] = x[i] * dv;
        if (i == 0) rowptr[N_NODES] = N_EDGES;
    }
}

// fill colv (atomic-free) + scatter xd[src] into sacc[dst] (layer-1 agg)
__global__ void k_fill(const int* __restrict__ ei, const int* __restrict__ rowptr,
                       const int* __restrict__ slot, const float* __restrict__ xd,
                       int* __restrict__ colv, float* __restrict__ sacc) {
    int t = blockIdx.x * blockDim.x + threadIdx.x;
    int e0 = t * 8;
    if (e0 >= N_EDGES) return;
    int d[8], sl[8], sr[8];
#pragma unroll
    for (int j = 0; j < 8; ++j) {
        d[j] = ei[N_EDGES + e0 + j];
        sl[j] = slot[e0 + j];
        sr[j] = ei[e0 + j];
    }
    int rp[8];
#pragma unroll
    for (int j = 0; j < 8; ++j) rp[j] = rowptr[d[j]];
    float xs[8];
#pragma unroll
    for (int j = 0; j < 8; ++j) xs[j] = xd[sr[j]];
#pragma unroll
    for (int j = 0; j < 8; ++j) colv[rp[j] + sl[j]] = sr[j];
#pragma unroll
    for (int j = 0; j < 8; ++j) atomicAdd(&sacc[d[j]], xs[j]);
}

// finalize sd[i] = (dinv_i*(sacc_i + xd_i), dinv_i)
__global__ void k_sd(const float* __restrict__ sacc, const float* __restrict__ xd,
                     const float* __restrict__ dinv, float2* __restrict__ sd) {
    int i = blockIdx.x * blockDim.x + threadIdx.x;
    if (i < N_NODES) {
        float dv = dinv[i];
        sd[i] = make_float2(dv * (sacc[i] + xd[i]), dv);
    }
}

// Layer-2 aggregation via rank-1 structure (exact fp32), lane-parallel gather
__global__ __launch_bounds__(256) void k_aggM(const int* __restrict__ rowptr,
                                              const int* __restrict__ colv,
                                              const float2* __restrict__ sd,
                                              const float* __restrict__ W1,
                                              const float* __restrict__ b1,
                                              ushort* __restrict__ M) {
    int wid = threadIdx.x >> 6, lane = threadIdx.x & 63;
    int node = blockIdx.x * 4 + wid;
    if (node >= N_NODES) return;
    int c4 = lane * 4;
    float4 w = *(const float4*)&W1[c4];
    float4 b = *(const float4*)&b1[c4];
    float2 self = sd[node];
    float a0 = self.y * fmaxf(fmaf(self.x, w.x, b.x), 0.f);
    float a1 = self.y * fmaxf(fmaf(self.x, w.y, b.y), 0.f);
    float a2 = self.y * fmaxf(fmaf(self.x, w.z, b.z), 0.f);
    float a3 = self.y * fmaxf(fmaf(self.x, w.w, b.w), 0.f);
    int s = rowptr[node], e = rowptr[node + 1];
    for (int base = s; base < e; base += 64) {
        int idx = base + lane;
        float2 p = make_float2(0.f, 0.f);
        if (idx < e) p = sd[colv[idx]];
        int rem = min(64, e - base);
        int k = 0;
        for (; k + 4 <= rem; k += 4) {
            float ps0 = __shfl(p.x, k),     pd0 = __shfl(p.y, k);
            float ps1 = __shfl(p.x, k + 1), pd1 = __shfl(p.y, k + 1);
            float ps2 = __shfl(p.x, k + 2), pd2 = __shfl(p.y, k + 2);
            float ps3 = __shfl(p.x, k + 3), pd3 = __shfl(p.y, k + 3);
            a0 += pd0 * fmaxf(fmaf(ps0, w.x, b.x), 0.f)
                + pd1 * fmaxf(fmaf(ps1, w.x, b.x), 0.f)
                + pd2 * fmaxf(fmaf(ps2, w.x, b.x), 0.f)
                + pd3 * fmaxf(fmaf(ps3, w.x, b.x), 0.f);
            a1 += pd0 * fmaxf(fmaf(ps0, w.y, b.y), 0.f)
                + pd1 * fmaxf(fmaf(ps1, w.y, b.y), 0.f)
                + pd2 * fmaxf(fmaf(ps2, w.y, b.y), 0.f)
                + pd3 * fmaxf(fmaf(ps3, w.y, b.y), 0.f);
            a2 += pd0 * fmaxf(fmaf(ps0, w.z, b.z), 0.f)
                + pd1 * fmaxf(fmaf(ps1, w.z, b.z), 0.f)
                + pd2 * fmaxf(fmaf(ps2, w.z, b.z), 0.f)
                + pd3 * fmaxf(fmaf(ps3, w.z, b.z), 0.f);
            a3 += pd0 * fmaxf(fmaf(ps0, w.w, b.w), 0.f)
                + pd1 * fmaxf(fmaf(ps1, w.w, b.w), 0.f)
                + pd2 * fmaxf(fmaf(ps2, w.w, b.w), 0.f)
                + pd3 * fmaxf(fmaf(ps3, w.w, b.w), 0.f);
        }
        for (; k < rem; ++k) {
            float ps = __shfl(p.x, k);
            float pd = __shfl(p.y, k);
            a0 += pd * fmaxf(fmaf(ps, w.x, b.x), 0.f);
            a1 += pd * fmaxf(fmaf(ps, w.y, b.y), 0.f);
            a2 += pd * fmaxf(fmaf(ps, w.z, b.z), 0.f);
            a3 += pd * fmaxf(fmaf(ps, w.w, b.w), 0.f);
        }
    }
    float dvi = self.y;
    ushort4 o;
    o.x = f2b(a0 * dvi);
    o.y = f2b(a1 * dvi);
    o.z = f2b(a2 * dvi);
    o.w = f2b(a3 * dvi);
    *(ushort4*)&M[(size_t)node * HDIM + c4] = o;
}

// pack W into bf16 MFMA fragment order; 2 matrices in 1 launch
__global__ __launch_bounds__(256) void k_packW2(const float* __restrict__ Wa,
                                                ushort* __restrict__ Wpa,
                                                const float* __restrict__ Wb,
                                                ushort* __restrict__ Wpb) {
    int bid = blockIdx.x;
    const float* W = (bid < 32) ? Wa : Wb;
    ushort* Wp = (bid < 32) ? Wpa : Wpb;
    int t = (bid & 31) * 256 + threadIdx.x;
    int lane = t & 63;
    int nt = (t >> 6) & 15;
    int k0 = t >> 10;
    int col = nt * 16 + (lane & 15);
    int kb = k0 * 32 + (lane >> 4) * 8;
    ushort o[8];
#pragma unroll
    for (int j = 0; j < 8; ++j) o[j] = f2b(W[(size_t)(kb + j) * HDIM + col]);
    *(ushort4*)&Wp[(size_t)t * 8 + 0] = make_ushort4(o[0], o[1], o[2], o[3]);
    *(ushort4*)&Wp[(size_t)t * 8 + 4] = make_ushort4(o[4], o[5], o[6], o[7]);
}

// ---------------- Fused gemm2+gemm3, 32 nodes/wave (2 MFMAs per Wp load) ----------------
__global__ __launch_bounds__(256) void k_g23(
    const ushort* __restrict__ M,
    const ushort* __restrict__ Wp2, const float* __restrict__ b2,
    const ushort* __restrict__ Wp3, const float* __restrict__ dinv,
    ushort* __restrict__ C) {
    __shared__ __align__(16) ushort lds[FB * 256];  // 64KB
    char* ldsb = (char*)lds;
    int tid = threadIdx.x;
    int wave = tid >> 6, lane = tid & 63;
    int l0 = wave * 32 + (lane & 15);
    int l1 = l0 + 16;
    int node0 = blockIdx.x * FB + l0;
    int node1 = node0 + 16;
    int kgrp = lane >> 4;
    bool ok0 = node0 < N_NODES, ok1 = node1 < N_NODES;
    unsigned swz = ((unsigned)(l0 & 7)) << 4;  // l1&7 == l0&7
    unsigned rowb0 = (unsigned)l0 * 512, rowb1 = (unsigned)l1 * 512;

    f32x4 acc0[16], acc1[16];
#pragma unroll
    for (int nt = 0; nt < 16; ++nt) {
        acc0[nt] = (f32x4){0.f, 0.f, 0.f, 0.f};
        acc1[nt] = (f32x4){0.f, 0.f, 0.f, 0.f};
    }

    // ---- gemm2: B-frags from global M rows; one Wp load feeds 2 MFMAs ----
    const ushort* ap0 = M + (size_t)(ok0 ? node0 : 0) * HDIM + kgrp * 8;
    const ushort* ap1 = M + (size_t)(ok1 ? node1 : 0) * HDIM + kgrp * 8;
#pragma unroll 1
    for (int k0 = 0; k0 < 8; ++k0) {
        bf16x8 bf0 = *(const bf16x8*)(ap0 + k0 * 32);
        bf16x8 bf1 = *(const bf16x8*)(ap1 + k0 * 32);
        if (!ok0) bf0 = (bf16x8){0, 0, 0, 0, 0, 0, 0, 0};
        if (!ok1) bf1 = (bf16x8){0, 0, 0, 0, 0, 0, 0, 0};
        const ushort* wp = Wp2 + ((size_t)k0 * 1024 + lane) * 8;
#pragma unroll
        for (int nt = 0; nt < 16; ++nt) {
            bf16x8 a = *(const bf16x8*)(wp + (size_t)nt * 512);
            acc0[nt] = __builtin_amdgcn_mfma_f32_16x16x32_bf16(a, bf0, acc0[nt], 0, 0, 0);
            acc1[nt] = __builtin_amdgcn_mfma_f32_16x16x32_bf16(a, bf1, acc1[nt], 0, 0, 0);
        }
    }

    // ---- h2 -> LDS (both rows) ----
#pragma unroll
    for (int nt = 0; nt < 16; ++nt) {
        int f = nt * 16 + kgrp * 4;
        float4 bv = *(const float4*)&b2[f];
        uint2 pk0, pk1;
        pk0.x = (unsigned)f2b(fmaxf(acc0[nt][0] + bv.x, 0.f)) |
                ((unsigned)f2b(fmaxf(acc0[nt][1] + bv.y, 0.f)) << 16);
        pk0.y = (unsigned)f2b(fmaxf(acc0[nt][2] + bv.z, 0.f)) |
                ((unsigned)f2b(fmaxf(acc0[nt][3] + bv.w, 0.f)) << 16);
        pk1.x = (unsigned)f2b(fmaxf(acc1[nt][0] + bv.x, 0.f)) |
                ((unsigned)f2b(fmaxf(acc1[nt][1] + bv.y, 0.f)) << 16);
        pk1.y = (unsigned)f2b(fmaxf(acc1[nt][2] + bv.z, 0.f)) |
                ((unsigned)f2b(fmaxf(acc1[nt][3] + bv.w, 0.f)) << 16);
        unsigned fo = ((unsigned)(f * 2)) ^ swz;
        *(uint2*)(ldsb + rowb0 + fo) = pk0;
        *(uint2*)(ldsb + rowb1 + fo) = pk1;
    }
    __syncthreads();

    // ---- gemm3: B-frags from LDS; one Wp load feeds 2 MFMAs ----
#pragma unroll
    for (int nt = 0; nt < 16; ++nt) {
        acc0[nt] = (f32x4){0.f, 0.f, 0.f, 0.f};
        acc1[nt] = (f32x4){0.f, 0.f, 0.f, 0.f};
    }
#pragma unroll 1
    for (int k0 = 0; k0 < 8; ++k0) {
        unsigned ko = ((unsigned)(16 * kgrp + 64 * k0)) ^ swz;
        bf16x8 bf0 = *(const bf16x8*)(ldsb + rowb0 + ko);
        bf16x8 bf1 = *(const bf16x8*)(ldsb + rowb1 + ko);
        const ushort* wp = Wp3 + ((size_t)k0 * 1024 + lane) * 8;
#pragma unroll
        for (int nt = 0; nt < 16; ++nt) {
            bf16x8 a = *(const bf16x8*)(wp + (size_t)nt * 512);
            acc0[nt] = __builtin_amdgcn_mfma_f32_16x16x32_bf16(a, bf0, acc0[nt], 0, 0, 0);
            acc1[nt] = __builtin_amdgcn_mfma_f32_16x16x32_bf16(a, bf1, acc1[nt], 0, 0, 0);
        }
    }
    if (ok0) {
        float dv = dinv[node0];
        size_t base = (size_t)node0 * HDIM + kgrp * 4;
#pragma unroll
        for (int nt = 0; nt < 16; ++nt) {
            ushort4 o;
            o.x = f2b(acc0[nt][0] * dv);
            o.y = f2b(acc0[nt][1] * dv);
            o.z = f2b(acc0[nt][2] * dv);
            o.w = f2b(acc0[nt][3] * dv);
            *(ushort4*)&C[base + nt * 16] = o;
        }
    }
    if (ok1) {
        float dv = dinv[node1];
        size_t base = (size_t)node1 * HDIM + kgrp * 4;
#pragma unroll
        for (int nt = 0; nt < 16; ++nt) {
            ushort4 o;
            o.x = f2b(acc1[nt][0] * dv);
            o.y = f2b(acc1[nt][1] * dv);
            o.z = f2b(acc1[nt][2] * dv);
            o.w = f2b(acc1[nt][3] * dv);
            *(ushort4*)&C[base + nt * 16] = o;
        }
    }
}

// ---------------- Fused layer-3 aggregation + mean-pool partials ----------------
__global__ __launch_bounds__(1024) void k_agg_pool(
    const ushort* __restrict__ g, const int* __restrict__ rowptr,
    const int* __restrict__ colv, const float* __restrict__ dinv,
    const float* __restrict__ bias, const int* __restrict__ batch,
    float* __restrict__ pooled) {
    __shared__ float srow[16][256];
    __shared__ int wbid[16];
    int wid = threadIdx.x >> 6, lane = threadIdx.x & 63;
    int node = blockIdx.x * 16 + wid;
    bool ok = node < N_NODES;
    int nd = ok ? node : N_NODES - 1;
    int half = lane >> 5;
    int l32 = lane & 31;
    int c8 = l32 * 8;
    float acc[8];
    if (half == 0) {
        u16x8 v = *(const u16x8*)&g[(size_t)nd * HDIM + c8];
#pragma unroll
        for (int j = 0; j < 8; ++j) acc[j] = b2f(v[j]);
    } else {
#pragma unroll
        for (int j = 0; j < 8; ++j) acc[j] = 0.f;
    }
    int s = rowptr[nd], e = rowptr[nd + 1];
    int i = s;
    for (; i + 8 <= e; i += 8) {
        int base = i + half * 4;
        int n0 = colv[base + 0];
        int n1 = colv[base + 1];
        int n2 = colv[base + 2];
        int n3 = colv[base + 3];
        u16x8 v0 = *(const u16x8*)&g[(size_t)n0 * HDIM + c8];
        u16x8 v1 = *(const u16x8*)&g[(size_t)n1 * HDIM + c8];
        u16x8 v2 = *(const u16x8*)&g[(size_t)n2 * HDIM + c8];
        u16x8 v3 = *(const u16x8*)&g[(size_t)n3 * HDIM + c8];
#pragma unroll
        for (int j = 0; j < 8; ++j)
            acc[j] += (b2f(v0[j]) + b2f(v1[j])) + (b2f(v2[j]) + b2f(v3[j]));
    }
    if (i + 4 <= e) {
        int base = i + half * 2;
        int n0 = colv[base + 0];
        int n1 = colv[base + 1];
        u16x8 v0 = *(const u16x8*)&g[(size_t)n0 * HDIM + c8];
        u16x8 v1 = *(const u16x8*)&g[(size_t)n1 * HDIM + c8];
#pragma unroll
        for (int j = 0; j < 8; ++j) acc[j] += b2f(v0[j]) + b2f(v1[j]);
        i += 4;
    }
    if (i + 2 <= e) {
        int n = colv[i + half];
        u16x8 v = *(const u16x8*)&g[(size_t)n * HDIM + c8];
#pragma unroll
        for (int j = 0; j < 8; ++j) acc[j] += b2f(v[j]);
        i += 2;
    }
    if (i < e && half == 0) {
        int n = colv[i];
        u16x8 v = *(const u16x8*)&g[(size_t)n * HDIM + c8];
#pragma unroll
        for (int j = 0; j < 8; ++j) acc[j] += b2f(v[j]);
    }
#pragma unroll
    for (int j = 0; j < 8; ++j) acc[j] += __shfl_xor(acc[j], 32);
    if (half == 0) {
        float dv = dinv[nd];
        float4 bl = *(const float4*)&bias[c8];
        float4 bh = *(const float4*)&bias[c8 + 4];
        float bj[8] = {bl.x, bl.y, bl.z, bl.w, bh.x, bh.y, bh.z, bh.w};
#pragma unroll
        for (int j = 0; j < 8; ++j) {
            float v = fmaxf(fmaf(acc[j], dv, bj[j]), 0.f);
            srow[wid][c8 + j] = ok ? v : 0.f;
        }
        if (l32 == 0) wbid[wid] = batch[nd];
    }
    __syncthreads();
    if (threadIdx.x < 256) {
        int j = threadIdx.x;
        float run = srow[0][j];
        int cur = wbid[0];
        for (int w = 1; w < 16; ++w) {
            int b = wbid[w];
            if (b != cur) {
                atomicAdd(&pooled[cur * HDIM + j], run);
                run = 0.f;
                cur = b;
            }
            run += srow[w][j];
        }
        atomicAdd(&pooled[cur * HDIM + j], run);
    }
}

__global__ __launch_bounds__(128) void k_bounds(const int* __restrict__ batch,
                                                int* __restrict__ startb,
                                                float* __restrict__ pooled) {
    int t = threadIdx.x;
    if (t <= NGRAPH) {
        int lo = 0, hi = N_NODES;
        while (lo < hi) {
            int mid = (lo + hi) >> 1;
            if (batch[mid] < t) lo = mid + 1; else hi = mid;
        }
        startb[t] = lo;
    }
    for (int i = t; i < NGRAPH * HDIM; i += 128) pooled[i] = 0.f;
}

__global__ __launch_bounds__(128) void k_mlp(const float* __restrict__ pooled,
                                             const int* __restrict__ startb,
                                             const float* __restrict__ svm,
                                             const float* __restrict__ Wf1,
                                             const float* __restrict__ bf1,
                                             const float* __restrict__ Wf2,
                                             const float* __restrict__ bf2,
                                             float* __restrict__ out) {
    __shared__ float fl[257];
    __shared__ float hl[128];
    int b = blockIdx.x;
    int j = threadIdx.x;
    float cntb = fmaxf((float)(startb[b + 1] - startb[b]), 1.0f);
    for (int k = j; k < 256; k += 128) fl[k] = pooled[b * HDIM + k] / cntb;
    if (j == 0) fl[256] = svm[b];
    __syncthreads();
    float acc = bf1[j];
    for (int k = 0; k < 257; ++k) acc = fmaf(fl[k], Wf1[k * 128 + j], acc);
    hl[j] = fmaxf(acc, 0.f);
    __syncthreads();
    if (j < 6) {
        float o = bf2[j];
        for (int k = 0; k < 128; ++k) o = fmaf(hl[k], Wf2[k * 6 + j], o);
        out[b * 6 + j] = o;
    }
}

static inline size_t al256(size_t x) { return (x + 255) & ~(size_t)255; }

extern "C" void kernel_launch(void* const* d_in, const int* in_sizes, int n_in,
                              void* d_out, int out_size, void* d_ws, size_t ws_size,
                              hipStream_t stream) {
    const float* x    = (const float*)d_in[0];
    const int*   ei   = (const int*)d_in[1];
    const int*   batch= (const int*)d_in[2];
    const float* svm  = (const float*)d_in[3];
    const float* W1   = (const float*)d_in[4];
    const float* b1   = (const float*)d_in[5];
    const float* W2   = (const float*)d_in[6];
    const float* b2   = (const float*)d_in[7];
    const float* W3   = (const float*)d_in[8];
    const float* b3   = (const float*)d_in[9];
    const float* Wf1  = (const float*)d_in[10];
    const float* bf1  = (const float*)d_in[11];
    const float* Wf2  = (const float*)d_in[12];
    const float* bf2  = (const float*)d_in[13];
    float* out = (float*)d_out;

    char* w = (char*)d_ws;
    int*    cnt    = (int*)w;    w += al256((size_t)N_NODES * 4);
    float*  sacc   = (float*)w;  w += al256((size_t)N_NODES * 4);
    int*    rowptr = (int*)w;    w += al256((size_t)(N_NODES + 1) * 4);
    int*    slot   = (int*)w;    w += al256((size_t)N_EDGES * 4);
    int*    colv   = (int*)w;    w += al256((size_t)N_EDGES * 4);
    float*  dinv   = (float*)w;  w += al256((size_t)N_NODES * 4);
    float*  xd     = (float*)w;  w += al256((size_t)N_NODES * 4);
    float2* sd     = (float2*)w; w += al256((size_t)N_NODES * 8);
    int*    startb = (int*)w;    w += al256(65 * 4);
    int*    bsum   = (int*)w;    w += al256((size_t)SCAN_NB * 4);
    float*  pooled = (float*)w;  w += al256((size_t)NGRAPH * HDIM * 4);
    ushort* Wp2    = (ushort*)w; w += al256((size_t)8 * 16 * 64 * 8 * 2);
    ushort* Wp3    = (ushort*)w; w += al256((size_t)8 * 16 * 64 * 8 * 2);
    ushort* bigA   = (ushort*)w; w += al256((size_t)N_NODES * HDIM * 2);
    ushort* bigB   = (ushort*)w; w += al256((size_t)N_NODES * HDIM * 2);

    const int nblkN = (N_NODES + 255) / 256;
    const int nblkW = (N_NODES + 3) / 4;
    const int nblkF = (N_NODES + FB - 1) / FB;
    const int nblkP = (N_NODES + 15) / 16;

    // CSR build (+ fused layer-1 scalar scatter)
    hipMemsetAsync(cnt, 0, (size_t)N_NODES * 4, stream);
    hipMemsetAsync(sacc, 0, (size_t)N_NODES * 4, stream);
    k_count<<<(N_EDGES / 16 + 255) / 256, 256, 0, stream>>>(ei, cnt, slot);
    k_scan1<<<SCAN_NB, SCAN_BLK, 0, stream>>>(cnt, rowptr, bsum);
    k_scan2<<<1, 128, 0, stream>>>(bsum);
    k_dinv_fix<<<nblkN, 256, 0, stream>>>(cnt, x, bsum, dinv, xd, rowptr);
    k_fill<<<(N_EDGES / 8 + 255) / 256, 256, 0, stream>>>(ei, rowptr, slot, xd, colv, sacc);
    k_sd<<<nblkN, 256, 0, stream>>>(sacc, xd, dinv, sd);

    // W packing
    k_packW2<<<64, 256, 0, stream>>>(W2, Wp2, W3, Wp3);

    // layer 2 aggregation (rank-1, scalar gather) -> M (bigA)
    k_aggM<<<nblkW, 256, 0, stream>>>(rowptr, colv, sd, W1, b1, bigA);

    // fused gemm2+gemm3 (h2 in LDS, 32 nodes/wave) -> g3 (bigB)
    k_g23<<<nblkF, 256, 0, stream>>>(bigA, Wp2, b2, Wp3, dinv, bigB);

    // pooled zero + startb
    k_bounds<<<1, 128, 0, stream>>>(batch, startb, pooled);

    // fused layer-3 aggregation + mean-pool partial sums
    k_agg_pool<<<nblkP, 1024, 0, stream>>>(bigB, rowptr, colv, dinv, b3, batch, pooled);

    // head
    k_mlp<<<NGRAPH, 128, 0, stream>>>(pooled, startb, svm, Wf1, bf1, Wf2, bf2, out);
}

// Round 14
// 416.285 us; speedup vs baseline: 1.1910x; 1.1910x over previous
//
#include <hip/hip_runtime.h>
#include <math.h>

#define N_NODES 100000
#define N_EDGES 1600000
#define HDIM    256
#define NGRAPH  64

#define SCAN_BLK 1024
#define SCAN_NB  ((N_NODES + SCAN_BLK - 1) / SCAN_BLK)  // 98

#define FB 64  // nodes per fused-gemm block

typedef __attribute__((ext_vector_type(8))) short bf16x8;
typedef __attribute__((ext_vector_type(4))) float f32x4;
typedef __attribute__((ext_vector_type(8))) unsigned short u16x8;

__device__ __forceinline__ ushort f2b(float f) {
    union { float f; unsigned u; } x; x.f = f;
    unsigned u = x.u;
    unsigned r = u + 0x7fffu + ((u >> 16) & 1u);
    return (ushort)(r >> 16);
}
__device__ __forceinline__ float b2f(ushort h) {
    union { unsigned u; float f; } x; x.u = ((unsigned)h) << 16;
    return x.f;
}

// ---------------- CSR build ----------------
__global__ void k_count(const int* __restrict__ ei, int* __restrict__ cnt,
                        int* __restrict__ slot) {
    int t = blockIdx.x * blockDim.x + threadIdx.x;
    int e0 = t * 16;
    if (e0 >= N_EDGES) return;
    int d[16];
#pragma unroll
    for (int j = 0; j < 16; ++j) d[j] = ei[N_EDGES + e0 + j];
    int s[16];
#pragma unroll
    for (int j = 0; j < 16; ++j) s[j] = atomicAdd(&cnt[d[j]], 1);
#pragma unroll
    for (int j = 0; j < 16; ++j) slot[e0 + j] = s[j];
}

__global__ __launch_bounds__(1024) void k_scan1(const int* __restrict__ cnt,
                                                int* __restrict__ rowptr,
                                                int* __restrict__ bsum) {
    __shared__ int lds[SCAN_BLK];
    int t = threadIdx.x;
    int i = blockIdx.x * SCAN_BLK + t;
    int v = (i < N_NODES) ? cnt[i] : 0;
    lds[t] = v;
    __syncthreads();
    for (int off = 1; off < SCAN_BLK; off <<= 1) {
        int u = (t >= off) ? lds[t - off] : 0;
        __syncthreads();
        lds[t] += u;
        __syncthreads();
    }
    if (i < N_NODES) rowptr[i] = lds[t] - v;
    if (t == SCAN_BLK - 1) bsum[blockIdx.x] = lds[t];
}

__global__ __launch_bounds__(128) void k_scan2(int* __restrict__ bsum) {
    __shared__ int lds[128];
    int t = threadIdx.x;
    int v = (t < SCAN_NB) ? bsum[t] : 0;
    lds[t] = v;
    __syncthreads();
    for (int off = 1; off < 128; off <<= 1) {
        int u = (t >= off) ? lds[t - off] : 0;
        __syncthreads();
        lds[t] += u;
        __syncthreads();
    }
    if (t < SCAN_NB) bsum[t] = lds[t] - v;
}

__global__ void k_dinv_fix(const int* __restrict__ cnt, const float* __restrict__ x,
                           const int* __restrict__ bsum,
                           float* __restrict__ dinv, float* __restrict__ xd,
                           int* __restrict__ rowptr) {
    int i = blockIdx.x * blockDim.x + threadIdx.x;
    if (i < N_NODES) {
        rowptr[i] += bsum[i >> 10];
        float d = (float)(cnt[i] + 1);
        float dv = 1.0f / sqrtf(d);
        dinv[i] = dv;
        xd[i] = x[i] * dv;
        if (i == 0) rowptr[N_NODES] = N_EDGES;
    }
}

__global__ void k_fill(const int* __restrict__ ei, const int* __restrict__ rowptr,
                       const int* __restrict__ slot, int* __restrict__ colv) {
    int t = blockIdx.x * blockDim.x + threadIdx.x;
    int e0 = t * 8;
    if (e0 >= N_EDGES) return;
    int d[8], sl[8], sr[8];
#pragma unroll
    for (int j = 0; j < 8; ++j) {
        d[j] = ei[N_EDGES + e0 + j];
        sl[j] = slot[e0 + j];
        sr[j] = ei[e0 + j];
    }
    int rp[8];
#pragma unroll
    for (int j = 0; j < 8; ++j) rp[j] = rowptr[d[j]];
#pragma unroll
    for (int j = 0; j < 8; ++j) colv[rp[j] + sl[j]] = sr[j];
}

// layer-1 scalar aggregation, wave per node, lane-parallel gather
__global__ __launch_bounds__(256) void k_s(const int* __restrict__ rowptr,
                                           const int* __restrict__ colv,
                                           const float* __restrict__ xd,
                                           const float* __restrict__ dinv,
                                           float2* __restrict__ sd) {
    int wid = threadIdx.x >> 6, lane = threadIdx.x & 63;
    int node = blockIdx.x * 4 + wid;
    if (node >= N_NODES) return;
    int s = rowptr[node], e = rowptr[node + 1];
    float acc = 0.f;
    for (int idx = s + lane; idx < e; idx += 64) acc += xd[colv[idx]];
#pragma unroll
    for (int off = 32; off; off >>= 1) acc += __shfl_xor(acc, off);
    if (lane == 0) {
        float dv = dinv[node];
        sd[node] = make_float2(dv * (acc + xd[node]), dv);
    }
}

// Layer-2 aggregation via rank-1 structure (exact fp32), lane-parallel gather
__global__ __launch_bounds__(256) void k_aggM(const int* __restrict__ rowptr,
                                              const int* __restrict__ colv,
                                              const float2* __restrict__ sd,
                                              const float* __restrict__ W1,
                                              const float* __restrict__ b1,
                                              ushort* __restrict__ M) {
    int wid = threadIdx.x >> 6, lane = threadIdx.x & 63;
    int node = blockIdx.x * 4 + wid;
    if (node >= N_NODES) return;
    int c4 = lane * 4;
    float4 w = *(const float4*)&W1[c4];
    float4 b = *(const float4*)&b1[c4];
    float2 self = sd[node];
    float a0 = self.y * fmaxf(fmaf(self.x, w.x, b.x), 0.f);
    float a1 = self.y * fmaxf(fmaf(self.x, w.y, b.y), 0.f);
    float a2 = self.y * fmaxf(fmaf(self.x, w.z, b.z), 0.f);
    float a3 = self.y * fmaxf(fmaf(self.x, w.w, b.w), 0.f);
    int s = rowptr[node], e = rowptr[node + 1];
    for (int base = s; base < e; base += 64) {
        int idx = base + lane;
        float2 p = make_float2(0.f, 0.f);
        if (idx < e) p = sd[colv[idx]];
        int rem = min(64, e - base);
        int k = 0;
        for (; k + 4 <= rem; k += 4) {
            float ps0 = __shfl(p.x, k),     pd0 = __shfl(p.y, k);
            float ps1 = __shfl(p.x, k + 1), pd1 = __shfl(p.y, k + 1);
            float ps2 = __shfl(p.x, k + 2), pd2 = __shfl(p.y, k + 2);
            float ps3 = __shfl(p.x, k + 3), pd3 = __shfl(p.y, k + 3);
            a0 += pd0 * fmaxf(fmaf(ps0, w.x, b.x), 0.f)
                + pd1 * fmaxf(fmaf(ps1, w.x, b.x), 0.f)
                + pd2 * fmaxf(fmaf(ps2, w.x, b.x), 0.f)
                + pd3 * fmaxf(fmaf(ps3, w.x, b.x), 0.f);
            a1 += pd0 * fmaxf(fmaf(ps0, w.y, b.y), 0.f)
                + pd1 * fmaxf(fmaf(ps1, w.y, b.y), 0.f)
                + pd2 * fmaxf(fmaf(ps2, w.y, b.y), 0.f)
                + pd3 * fmaxf(fmaf(ps3, w.y, b.y), 0.f);
            a2 += pd0 * fmaxf(fmaf(ps0, w.z, b.z), 0.f)
                + pd1 * fmaxf(fmaf(ps1, w.z, b.z), 0.f)
                + pd2 * fmaxf(fmaf(ps2, w.z, b.z), 0.f)
                + pd3 * fmaxf(fmaf(ps3, w.z, b.z), 0.f);
            a3 += pd0 * fmaxf(fmaf(ps0, w.w, b.w), 0.f)
                + pd1 * fmaxf(fmaf(ps1, w.w, b.w), 0.f)
                + pd2 * fmaxf(fmaf(ps2, w.w, b.w), 0.f)
                + pd3 * fmaxf(fmaf(ps3, w.w, b.w), 0.f);
        }
        for (; k < rem; ++k) {
            float ps = __shfl(p.x, k);
            float pd = __shfl(p.y, k);
            a0 += pd * fmaxf(fmaf(ps, w.x, b.x), 0.f);
            a1 += pd * fmaxf(fmaf(ps, w.y, b.y), 0.f);
            a2 += pd * fmaxf(fmaf(ps, w.z, b.z), 0.f);
            a3 += pd * fmaxf(fmaf(ps, w.w, b.w), 0.f);
        }
    }
    float dvi = self.y;
    ushort4 o;
    o.x = f2b(a0 * dvi);
    o.y = f2b(a1 * dvi);
    o.z = f2b(a2 * dvi);
    o.w = f2b(a3 * dvi);
    *(ushort4*)&M[(size_t)node * HDIM + c4] = o;
}

// pack W into bf16 MFMA fragment order; 2 matrices in 1 launch
__global__ __launch_bounds__(256) void k_packW2(const float* __restrict__ Wa,
                                                ushort* __restrict__ Wpa,
                                                const float* __restrict__ Wb,
                                                ushort* __restrict__ Wpb) {
    int bid = blockIdx.x;
    const float* W = (bid < 32) ? Wa : Wb;
    ushort* Wp = (bid < 32) ? Wpa : Wpb;
    int t = (bid & 31) * 256 + threadIdx.x;
    int lane = t & 63;
    int nt = (t >> 6) & 15;
    int k0 = t >> 10;
    int col = nt * 16 + (lane & 15);
    int kb = k0 * 32 + (lane >> 4) * 8;
    ushort o[8];
#pragma unroll
    for (int j = 0; j < 8; ++j) o[j] = f2b(W[(size_t)(kb + j) * HDIM + col]);
    *(ushort4*)&Wp[(size_t)t * 8 + 0] = make_ushort4(o[0], o[1], o[2], o[3]);
    *(ushort4*)&Wp[(size_t)t * 8 + 4] = make_ushort4(o[4], o[5], o[6], o[7]);
}

// ---------------- Fused gemm2+gemm3 (h2 stays in LDS) ----------------
__global__ __launch_bounds__(256) void k_g23(
    const ushort* __restrict__ M,
    const ushort* __restrict__ Wp2, const float* __restrict__ b2,
    const ushort* __restrict__ Wp3, const float* __restrict__ dinv,
    ushort* __restrict__ C) {
    __shared__ __align__(16) ushort lds[FB * 256];  // 32KB
    char* ldsb = (char*)lds;
    int tid = threadIdx.x;
    int wave = tid >> 6, lane = tid & 63;
    int l = wave * 16 + (lane & 15);
    int node = blockIdx.x * FB + l;
    int kgrp = lane >> 4;
    bool ok = node < N_NODES;
    unsigned swz = ((unsigned)(l & 7)) << 4;
    unsigned rowb = (unsigned)l * 512;

    f32x4 acc[16];
#pragma unroll
    for (int nt = 0; nt < 16; ++nt) acc[nt] = (f32x4){0.f, 0.f, 0.f, 0.f};
    const ushort* ap = M + (size_t)(ok ? node : 0) * HDIM + kgrp * 8;
#pragma unroll 1
    for (int k0 = 0; k0 < 8; ++k0) {
        bf16x8 bf = *(const bf16x8*)(ap + k0 * 32);
        if (!ok) bf = (bf16x8){0, 0, 0, 0, 0, 0, 0, 0};
        const ushort* wp = Wp2 + ((size_t)k0 * 1024 + lane) * 8;
#pragma unroll
        for (int nt = 0; nt < 16; ++nt) {
            bf16x8 a = *(const bf16x8*)(wp + (size_t)nt * 512);
            acc[nt] = __builtin_amdgcn_mfma_f32_16x16x32_bf16(a, bf, acc[nt], 0, 0, 0);
        }
    }

#pragma unroll
    for (int nt = 0; nt < 16; ++nt) {
        int f = nt * 16 + kgrp * 4;
        float4 bv = *(const float4*)&b2[f];
        uint2 pk;
        pk.x = (unsigned)f2b(fmaxf(acc[nt][0] + bv.x, 0.f)) |
               ((unsigned)f2b(fmaxf(acc[nt][1] + bv.y, 0.f)) << 16);
        pk.y = (unsigned)f2b(fmaxf(acc[nt][2] + bv.z, 0.f)) |
               ((unsigned)f2b(fmaxf(acc[nt][3] + bv.w, 0.f)) << 16);
        *(uint2*)(ldsb + rowb + (((unsigned)(f * 2)) ^ swz)) = pk;
    }
    __syncthreads();

#pragma unroll
    for (int nt = 0; nt < 16; ++nt) acc[nt] = (f32x4){0.f, 0.f, 0.f, 0.f};
#pragma unroll 1
    for (int k0 = 0; k0 < 8; ++k0) {
        bf16x8 bf = *(const bf16x8*)(ldsb + rowb + (((unsigned)(16 * kgrp + 64 * k0)) ^ swz));
        const ushort* wp = Wp3 + ((size_t)k0 * 1024 + lane) * 8;
#pragma unroll
        for (int nt = 0; nt < 16; ++nt) {
            bf16x8 a = *(const bf16x8*)(wp + (size_t)nt * 512);
            acc[nt] = __builtin_amdgcn_mfma_f32_16x16x32_bf16(a, bf, acc[nt], 0, 0, 0);
        }
    }
    if (ok) {
        float dv = dinv[node];
        size_t base = (size_t)node * HDIM + kgrp * 4;
#pragma unroll
        for (int nt = 0; nt < 16; ++nt) {
            ushort4 o;
            o.x = f2b(acc[nt][0] * dv);
            o.y = f2b(acc[nt][1] * dv);
            o.z = f2b(acc[nt][2] * dv);
            o.w = f2b(acc[nt][3] * dv);
            *(ushort4*)&C[base + nt * 16] = o;
        }
    }
}

// ---------------- Fused layer-3 aggregation + mean-pool partials ----------------
// 8 waves/block (512 thr): shorter barrier tail than 16-wave version.
__global__ __launch_bounds__(512) void k_agg_pool(
    const ushort* __restrict__ g, const int* __restrict__ rowptr,
    const int* __restrict__ colv, const float* __restrict__ dinv,
    const float* __restrict__ bias, const int* __restrict__ batch,
    float* __restrict__ pooled) {
    __shared__ float srow[8][256];
    __shared__ int wbid[8];
    int wid = threadIdx.x >> 6, lane = threadIdx.x & 63;
    int node = blockIdx.x * 8 + wid;
    bool ok = node < N_NODES;
    int nd = ok ? node : N_NODES - 1;
    int half = lane >> 5;
    int l32 = lane & 31;
    int c8 = l32 * 8;
    float acc[8];
    if (half == 0) {
        u16x8 v = *(const u16x8*)&g[(size_t)nd * HDIM + c8];
#pragma unroll
        for (int j = 0; j < 8; ++j) acc[j] = b2f(v[j]);
    } else {
#pragma unroll
        for (int j = 0; j < 8; ++j) acc[j] = 0.f;
    }
    int s = rowptr[nd], e = rowptr[nd + 1];
    int i = s;
    for (; i + 8 <= e; i += 8) {
        int base = i + half * 4;
        int n0 = colv[base + 0];
        int n1 = colv[base + 1];
        int n2 = colv[base + 2];
        int n3 = colv[base + 3];
        u16x8 v0 = *(const u16x8*)&g[(size_t)n0 * HDIM + c8];
        u16x8 v1 = *(const u16x8*)&g[(size_t)n1 * HDIM + c8];
        u16x8 v2 = *(const u16x8*)&g[(size_t)n2 * HDIM + c8];
        u16x8 v3 = *(const u16x8*)&g[(size_t)n3 * HDIM + c8];
#pragma unroll
        for (int j = 0; j < 8; ++j)
            acc[j] += (b2f(v0[j]) + b2f(v1[j])) + (b2f(v2[j]) + b2f(v3[j]));
    }
    if (i + 4 <= e) {
        int base = i + half * 2;
        int n0 = colv[base + 0];
        int n1 = colv[base + 1];
        u16x8 v0 = *(const u16x8*)&g[(size_t)n0 * HDIM + c8];
        u16x8 v1 = *(const u16x8*)&g[(size_t)n1 * HDIM + c8];
#pragma unroll
        for (int j = 0; j < 8; ++j) acc[j] += b2f(v0[j]) + b2f(v1[j]);
        i += 4;
    }
    if (i + 2 <= e) {
        int n = colv[i + half];
        u16x8 v = *(const u16x8*)&g[(size_t)n * HDIM + c8];
#pragma unroll
        for (int j = 0; j < 8; ++j) acc[j] += b2f(v[j]);
        i += 2;
    }
    if (i < e && half == 0) {
        int n = colv[i];
        u16x8 v = *(const u16x8*)&g[(size_t)n * HDIM + c8];
#pragma unroll
        for (int j = 0; j < 8; ++j) acc[j] += b2f(v[j]);
    }
#pragma unroll
    for (int j = 0; j < 8; ++j) acc[j] += __shfl_xor(acc[j], 32);
    if (half == 0) {
        float dv = dinv[nd];
        float4 bl = *(const float4*)&bias[c8];
        float4 bh = *(const float4*)&bias[c8 + 4];
        float bj[8] = {bl.x, bl.y, bl.z, bl.w, bh.x, bh.y, bh.z, bh.w};
#pragma unroll
        for (int j = 0; j < 8; ++j) {
            float v = fmaxf(fmaf(acc[j], dv, bj[j]), 0.f);
            srow[wid][c8 + j] = ok ? v : 0.f;
        }
        if (l32 == 0) wbid[wid] = batch[nd];
    }
    __syncthreads();
    if (threadIdx.x < 256) {
        int j = threadIdx.x;
        float run = srow[0][j];
        int cur = wbid[0];
        for (int w = 1; w < 8; ++w) {
            int b = wbid[w];
            if (b != cur) {
                atomicAdd(&pooled[cur * HDIM + j], run);
                run = 0.f;
                cur = b;
            }
            run += srow[w][j];
        }
        atomicAdd(&pooled[cur * HDIM + j], run);
    }
}

__global__ __launch_bounds__(128) void k_bounds(const int* __restrict__ batch,
                                                int* __restrict__ startb,
                                                float* __restrict__ pooled) {
    int t = threadIdx.x;
    if (t <= NGRAPH) {
        int lo = 0, hi = N_NODES;
        while (lo < hi) {
            int mid = (lo + hi) >> 1;
            if (batch[mid] < t) lo = mid + 1; else hi = mid;
        }
        startb[t] = lo;
    }
    for (int i = t; i < NGRAPH * HDIM; i += 128) pooled[i] = 0.f;
}

__global__ __launch_bounds__(128) void k_mlp(const float* __restrict__ pooled,
                                             const int* __restrict__ startb,
                                             const float* __restrict__ svm,
                                             const float* __restrict__ Wf1,
                                             const float* __restrict__ bf1,
                                             const float* __restrict__ Wf2,
                                             const float* __restrict__ bf2,
                                             float* __restrict__ out) {
    __shared__ float fl[257];
    __shared__ float hl[128];
    int b = blockIdx.x;
    int j = threadIdx.x;
    float cntb = fmaxf((float)(startb[b + 1] - startb[b]), 1.0f);
    for (int k = j; k < 256; k += 128) fl[k] = pooled[b * HDIM + k] / cntb;
    if (j == 0) fl[256] = svm[b];
    __syncthreads();
    float acc = bf1[j];
    for (int k = 0; k < 257; ++k) acc = fmaf(fl[k], Wf1[k * 128 + j], acc);
    hl[j] = fmaxf(acc, 0.f);
    __syncthreads();
    if (j < 6) {
        float o = bf2[j];
        for (int k = 0; k < 128; ++k) o = fmaf(hl[k], Wf2[k * 6 + j], o);
        out[b * 6 + j] = o;
    }
}

static inline size_t al256(size_t x) { return (x + 255) & ~(size_t)255; }

extern "C" void kernel_launch(void* const* d_in, const int* in_sizes, int n_in,
                              void* d_out, int out_size, void* d_ws, size_t ws_size,
                              hipStream_t stream) {
    const float* x    = (const float*)d_in[0];
    const int*   ei   = (const int*)d_in[1];
    const int*   batch= (const int*)d_in[2];
    const float* svm  = (const float*)d_in[3];
    const float* W1   = (const float*)d_in[4];
    const float* b1   = (const float*)d_in[5];
    const float* W2   = (const float*)d_in[6];
    const float* b2   = (const float*)d_in[7];
    const float* W3   = (const float*)d_in[8];
    const float* b3   = (const float*)d_in[9];
    const float* Wf1  = (const float*)d_in[10];
    const float* bf1  = (const float*)d_in[11];
    const float* Wf2  = (const float*)d_in[12];
    const float* bf2  = (const float*)d_in[13];
    float* out = (float*)d_out;

    char* w = (char*)d_ws;
    int*    cnt    = (int*)w;    w += al256((size_t)N_NODES * 4);
    int*    rowptr = (int*)w;    w += al256((size_t)(N_NODES + 1) * 4);
    int*    slot   = (int*)w;    w += al256((size_t)N_EDGES * 4);
    int*    colv   = (int*)w;    w += al256((size_t)N_EDGES * 4);
    float*  dinv   = (float*)w;  w += al256((size_t)N_NODES * 4);
    float*  xd     = (float*)w;  w += al256((size_t)N_NODES * 4);
    float2* sd     = (float2*)w; w += al256((size_t)N_NODES * 8);
    int*    startb = (int*)w;    w += al256(65 * 4);
    int*    bsum   = (int*)w;    w += al256((size_t)SCAN_NB * 4);
    float*  pooled = (float*)w;  w += al256((size_t)NGRAPH * HDIM * 4);
    ushort* Wp2    = (ushort*)w; w += al256((size_t)8 * 16 * 64 * 8 * 2);
    ushort* Wp3    = (ushort*)w; w += al256((size_t)8 * 16 * 64 * 8 * 2);
    ushort* bigA   = (ushort*)w; w += al256((size_t)N_NODES * HDIM * 2);
    ushort* bigB   = (ushort*)w; w += al256((size_t)N_NODES * HDIM * 2);

    const int nblkN = (N_NODES + 255) / 256;
    const int nblkW = (N_NODES + 3) / 4;
    const int nblkF = (N_NODES + FB - 1) / FB;
    const int nblkP = (N_NODES + 7) / 8;

    // CSR build
    hipMemsetAsync(cnt, 0, (size_t)N_NODES * 4, stream);
    k_count<<<(N_EDGES / 16 + 255) / 256, 256, 0, stream>>>(ei, cnt, slot);
    k_scan1<<<SCAN_NB, SCAN_BLK, 0, stream>>>(cnt, rowptr, bsum);
    k_scan2<<<1, 128, 0, stream>>>(bsum);
    k_dinv_fix<<<nblkN, 256, 0, stream>>>(cnt, x, bsum, dinv, xd, rowptr);
    k_fill<<<(N_EDGES / 8 + 255) / 256, 256, 0, stream>>>(ei, rowptr, slot, colv);

    // W packing
    k_packW2<<<64, 256, 0, stream>>>(W2, Wp2, W3, Wp3);

    // layer 1 scalar agg -> (s, dinv) pairs
    k_s<<<nblkW, 256, 0, stream>>>(rowptr, colv, xd, dinv, sd);

    // layer 2 aggregation (rank-1, scalar gather) -> M (bigA)
    k_aggM<<<nblkW, 256, 0, stream>>>(rowptr, colv, sd, W1, b1, bigA);

    // fused gemm2+gemm3 (h2 in LDS) -> g3 (bigB)
    k_g23<<<nblkF, 256, 0, stream>>>(bigA, Wp2, b2, Wp3, dinv, bigB);

    // pooled zero + startb
    k_bounds<<<1, 128, 0, stream>>>(batch, startb, pooled);

    // fused layer-3 aggregation + mean-pool partial sums
    k_agg_pool<<<nblkP, 512, 0, stream>>>(bigB, rowptr, colv, dinv, b3, batch, pooled);

    // head
    k_mlp<<<NGRAPH, 128, 0, stream>>>(pooled, startb, svm, Wf1, bf1, Wf2, bf2, out);
}

// Round 15
// 404.064 us; speedup vs baseline: 1.2270x; 1.0302x over previous
//
#include <hip/hip_runtime.h>
#include <math.h>

#define N_NODES 100000
#define N_EDGES 1600000
#define HDIM    256
#define NGRAPH  64

#define SCAN_BLK 1024
#define SCAN_NB  ((N_NODES + SCAN_BLK - 1) / SCAN_BLK)  // 98
#define NBLK_DINV ((N_NODES + 255) / 256)               // 391

#define FB 64  // nodes per fused-gemm block

typedef __attribute__((ext_vector_type(8))) short bf16x8;
typedef __attribute__((ext_vector_type(4))) float f32x4;
typedef __attribute__((ext_vector_type(8))) unsigned short u16x8;

__device__ __forceinline__ ushort f2b(float f) {
    union { float f; unsigned u; } x; x.f = f;
    unsigned u = x.u;
    unsigned r = u + 0x7fffu + ((u >> 16) & 1u);
    return (ushort)(r >> 16);
}
__device__ __forceinline__ float b2f(ushort h) {
    union { unsigned u; float f; } x; x.u = ((unsigned)h) << 16;
    return x.f;
}

// ---------------- CSR build ----------------
__global__ void k_count(const int* __restrict__ ei, int* __restrict__ cnt,
                        int* __restrict__ slot) {
    int t = blockIdx.x * blockDim.x + threadIdx.x;
    int e0 = t * 16;
    if (e0 >= N_EDGES) return;
    int d[16];
#pragma unroll
    for (int j = 0; j < 16; ++j) d[j] = ei[N_EDGES + e0 + j];
    int s[16];
#pragma unroll
    for (int j = 0; j < 16; ++j) s[j] = atomicAdd(&cnt[d[j]], 1);
#pragma unroll
    for (int j = 0; j < 16; ++j) slot[e0 + j] = s[j];
}

__global__ __launch_bounds__(1024) void k_scan1(const int* __restrict__ cnt,
                                                int* __restrict__ rowptr,
                                                int* __restrict__ bsum) {
    __shared__ int lds[SCAN_BLK];
    int t = threadIdx.x;
    int i = blockIdx.x * SCAN_BLK + t;
    int v = (i < N_NODES) ? cnt[i] : 0;
    lds[t] = v;
    __syncthreads();
    for (int off = 1; off < SCAN_BLK; off <<= 1) {
        int u = (t >= off) ? lds[t - off] : 0;
        __syncthreads();
        lds[t] += u;
        __syncthreads();
    }
    if (i < N_NODES) rowptr[i] = lds[t] - v;
    if (t == SCAN_BLK - 1) bsum[blockIdx.x] = lds[t];
}

// scan of block totals + graph-boundary search + pooled zero (merged)
__global__ __launch_bounds__(128) void k_scan2b(int* __restrict__ bsum,
                                                const int* __restrict__ batch,
                                                int* __restrict__ startb,
                                                float* __restrict__ pooled) {
    __shared__ int lds[128];
    int t = threadIdx.x;
    int v = (t < SCAN_NB) ? bsum[t] : 0;
    lds[t] = v;
    __syncthreads();
    for (int off = 1; off < 128; off <<= 1) {
        int u = (t >= off) ? lds[t - off] : 0;
        __syncthreads();
        lds[t] += u;
        __syncthreads();
    }
    if (t < SCAN_NB) bsum[t] = lds[t] - v;
    // bounds + pooled zero (independent work)
    if (t <= NGRAPH) {
        int lo = 0, hi = N_NODES;
        while (lo < hi) {
            int mid = (lo + hi) >> 1;
            if (batch[mid] < t) lo = mid + 1; else hi = mid;
        }
        startb[t] = lo;
    }
    for (int i = t; i < NGRAPH * HDIM; i += 128) pooled[i] = 0.f;
}

// rowptr offset-add + dinv/xd init, with W-pack blocks appended (merged)
__global__ __launch_bounds__(256) void k_dinv_pack(
    const int* __restrict__ cnt, const float* __restrict__ x,
    const int* __restrict__ bsum, float* __restrict__ dinv,
    float* __restrict__ xd, int* __restrict__ rowptr,
    const float* __restrict__ W2, ushort* __restrict__ Wp2,
    const float* __restrict__ W3, ushort* __restrict__ Wp3) {
    int bid = blockIdx.x;
    if (bid < NBLK_DINV) {
        int i = bid * 256 + threadIdx.x;
        if (i < N_NODES) {
            rowptr[i] += bsum[i >> 10];
            float d = (float)(cnt[i] + 1);
            float dv = 1.0f / sqrtf(d);
            dinv[i] = dv;
            xd[i] = x[i] * dv;
            if (i == 0) rowptr[N_NODES] = N_EDGES;
        }
    } else {
        int pb = bid - NBLK_DINV;  // [0,64)
        const float* W = (pb < 32) ? W2 : W3;
        ushort* Wp = (pb < 32) ? Wp2 : Wp3;
        int t = (pb & 31) * 256 + threadIdx.x;  // [0, 8192)
        int lane = t & 63;
        int nt = (t >> 6) & 15;
        int k0 = t >> 10;
        int col = nt * 16 + (lane & 15);
        int kb = k0 * 32 + (lane >> 4) * 8;
        ushort o[8];
#pragma unroll
        for (int j = 0; j < 8; ++j) o[j] = f2b(W[(size_t)(kb + j) * HDIM + col]);
        *(ushort4*)&Wp[(size_t)t * 8 + 0] = make_ushort4(o[0], o[1], o[2], o[3]);
        *(ushort4*)&Wp[(size_t)t * 8 + 4] = make_ushort4(o[4], o[5], o[6], o[7]);
    }
}

__global__ void k_fill(const int* __restrict__ ei, const int* __restrict__ rowptr,
                       const int* __restrict__ slot, int* __restrict__ colv) {
    int t = blockIdx.x * blockDim.x + threadIdx.x;
    int e0 = t * 8;
    if (e0 >= N_EDGES) return;
    int d[8], sl[8], sr[8];
#pragma unroll
    for (int j = 0; j < 8; ++j) {
        d[j] = ei[N_EDGES + e0 + j];
        sl[j] = slot[e0 + j];
        sr[j] = ei[e0 + j];
    }
    int rp[8];
#pragma unroll
    for (int j = 0; j < 8; ++j) rp[j] = rowptr[d[j]];
#pragma unroll
    for (int j = 0; j < 8; ++j) colv[rp[j] + sl[j]] = sr[j];
}

// layer-1 scalar aggregation: 16 lanes per node (4 nodes/wave) — better lane use
__global__ __launch_bounds__(256) void k_s(const int* __restrict__ rowptr,
                                           const int* __restrict__ colv,
                                           const float* __restrict__ xd,
                                           const float* __restrict__ dinv,
                                           float2* __restrict__ sd) {
    int tid = threadIdx.x;
    int wid = tid >> 6, lane = tid & 63;
    int sub = lane >> 4, l16 = lane & 15;
    int node = blockIdx.x * 16 + wid * 4 + sub;
    if (node >= N_NODES) return;
    int s = rowptr[node], e = rowptr[node + 1];
    float acc = 0.f;
    for (int idx = s + l16; idx < e; idx += 16) acc += xd[colv[idx]];
    acc += __shfl_xor(acc, 8);
    acc += __shfl_xor(acc, 4);
    acc += __shfl_xor(acc, 2);
    acc += __shfl_xor(acc, 1);
    if (l16 == 0) {
        float dv = dinv[node];
        sd[node] = make_float2(dv * (acc + xd[node]), dv);
    }
}

// Layer-2 aggregation via rank-1 structure (exact fp32), lane-parallel gather
__global__ __launch_bounds__(256) void k_aggM(const int* __restrict__ rowptr,
                                              const int* __restrict__ colv,
                                              const float2* __restrict__ sd,
                                              const float* __restrict__ W1,
                                              const float* __restrict__ b1,
                                              ushort* __restrict__ M) {
    int wid = threadIdx.x >> 6, lane = threadIdx.x & 63;
    int node = blockIdx.x * 4 + wid;
    if (node >= N_NODES) return;
    int c4 = lane * 4;
    float4 w = *(const float4*)&W1[c4];
    float4 b = *(const float4*)&b1[c4];
    float2 self = sd[node];
    float a0 = self.y * fmaxf(fmaf(self.x, w.x, b.x), 0.f);
    float a1 = self.y * fmaxf(fmaf(self.x, w.y, b.y), 0.f);
    float a2 = self.y * fmaxf(fmaf(self.x, w.z, b.z), 0.f);
    float a3 = self.y * fmaxf(fmaf(self.x, w.w, b.w), 0.f);
    int s = rowptr[node], e = rowptr[node + 1];
    for (int base = s; base < e; base += 64) {
        int idx = base + lane;
        float2 p = make_float2(0.f, 0.f);
        if (idx < e) p = sd[colv[idx]];
        int rem = min(64, e - base);
        int k = 0;
        for (; k + 4 <= rem; k += 4) {
            float ps0 = __shfl(p.x, k),     pd0 = __shfl(p.y, k);
            float ps1 = __shfl(p.x, k + 1), pd1 = __shfl(p.y, k + 1);
            float ps2 = __shfl(p.x, k + 2), pd2 = __shfl(p.y, k + 2);
            float ps3 = __shfl(p.x, k + 3), pd3 = __shfl(p.y, k + 3);
            a0 += pd0 * fmaxf(fmaf(ps0, w.x, b.x), 0.f)
                + pd1 * fmaxf(fmaf(ps1, w.x, b.x), 0.f)
                + pd2 * fmaxf(fmaf(ps2, w.x, b.x), 0.f)
                + pd3 * fmaxf(fmaf(ps3, w.x, b.x), 0.f);
            a1 += pd0 * fmaxf(fmaf(ps0, w.y, b.y), 0.f)
                + pd1 * fmaxf(fmaf(ps1, w.y, b.y), 0.f)
                + pd2 * fmaxf(fmaf(ps2, w.y, b.y), 0.f)
                + pd3 * fmaxf(fmaf(ps3, w.y, b.y), 0.f);
            a2 += pd0 * fmaxf(fmaf(ps0, w.z, b.z), 0.f)
                + pd1 * fmaxf(fmaf(ps1, w.z, b.z), 0.f)
                + pd2 * fmaxf(fmaf(ps2, w.z, b.z), 0.f)
                + pd3 * fmaxf(fmaf(ps3, w.z, b.z), 0.f);
            a3 += pd0 * fmaxf(fmaf(ps0, w.w, b.w), 0.f)
                + pd1 * fmaxf(fmaf(ps1, w.w, b.w), 0.f)
                + pd2 * fmaxf(fmaf(ps2, w.w, b.w), 0.f)
                + pd3 * fmaxf(fmaf(ps3, w.w, b.w), 0.f);
        }
        for (; k < rem; ++k) {
            float ps = __shfl(p.x, k);
            float pd = __shfl(p.y, k);
            a0 += pd * fmaxf(fmaf(ps, w.x, b.x), 0.f);
            a1 += pd * fmaxf(fmaf(ps, w.y, b.y), 0.f);
            a2 += pd * fmaxf(fmaf(ps, w.z, b.z), 0.f);
            a3 += pd * fmaxf(fmaf(ps, w.w, b.w), 0.f);
        }
    }
    float dvi = self.y;
    ushort4 o;
    o.x = f2b(a0 * dvi);
    o.y = f2b(a1 * dvi);
    o.z = f2b(a2 * dvi);
    o.w = f2b(a3 * dvi);
    *(ushort4*)&M[(size_t)node * HDIM + c4] = o;
}

// ---------------- Fused gemm2+gemm3 (h2 stays in LDS) ----------------
__global__ __launch_bounds__(256) void k_g23(
    const ushort* __restrict__ M,
    const ushort* __restrict__ Wp2, const float* __restrict__ b2,
    const ushort* __restrict__ Wp3, const float* __restrict__ dinv,
    ushort* __restrict__ C) {
    __shared__ __align__(16) ushort lds[FB * 256];  // 32KB
    char* ldsb = (char*)lds;
    int tid = threadIdx.x;
    int wave = tid >> 6, lane = tid & 63;
    int l = wave * 16 + (lane & 15);
    int node = blockIdx.x * FB + l;
    int kgrp = lane >> 4;
    bool ok = node < N_NODES;
    unsigned swz = ((unsigned)(l & 7)) << 4;
    unsigned rowb = (unsigned)l * 512;

    f32x4 acc[16];
#pragma unroll
    for (int nt = 0; nt < 16; ++nt) acc[nt] = (f32x4){0.f, 0.f, 0.f, 0.f};
    const ushort* ap = M + (size_t)(ok ? node : 0) * HDIM + kgrp * 8;
#pragma unroll 1
    for (int k0 = 0; k0 < 8; ++k0) {
        bf16x8 bf = *(const bf16x8*)(ap + k0 * 32);
        if (!ok) bf = (bf16x8){0, 0, 0, 0, 0, 0, 0, 0};
        const ushort* wp = Wp2 + ((size_t)k0 * 1024 + lane) * 8;
#pragma unroll
        for (int nt = 0; nt < 16; ++nt) {
            bf16x8 a = *(const bf16x8*)(wp + (size_t)nt * 512);
            acc[nt] = __builtin_amdgcn_mfma_f32_16x16x32_bf16(a, bf, acc[nt], 0, 0, 0);
        }
    }

#pragma unroll
    for (int nt = 0; nt < 16; ++nt) {
        int f = nt * 16 + kgrp * 4;
        float4 bv = *(const float4*)&b2[f];
        uint2 pk;
        pk.x = (unsigned)f2b(fmaxf(acc[nt][0] + bv.x, 0.f)) |
               ((unsigned)f2b(fmaxf(acc[nt][1] + bv.y, 0.f)) << 16);
        pk.y = (unsigned)f2b(fmaxf(acc[nt][2] + bv.z, 0.f)) |
               ((unsigned)f2b(fmaxf(acc[nt][3] + bv.w, 0.f)) << 16);
        *(uint2*)(ldsb + rowb + (((unsigned)(f * 2)) ^ swz)) = pk;
    }
    __syncthreads();

#pragma unroll
    for (int nt = 0; nt < 16; ++nt) acc[nt] = (f32x4){0.f, 0.f, 0.f, 0.f};
#pragma unroll 1
    for (int k0 = 0; k0 < 8; ++k0) {
        bf16x8 bf = *(const bf16x8*)(ldsb + rowb + (((unsigned)(16 * kgrp + 64 * k0)) ^ swz));
        const ushort* wp = Wp3 + ((size_t)k0 * 1024 + lane) * 8;
#pragma unroll
        for (int nt = 0; nt < 16; ++nt) {
            bf16x8 a = *(const bf16x8*)(wp + (size_t)nt * 512);
            acc[nt] = __builtin_amdgcn_mfma_f32_16x16x32_bf16(a, bf, acc[nt], 0, 0, 0);
        }
    }
    if (ok) {
        float dv = dinv[node];
        size_t base = (size_t)node * HDIM + kgrp * 4;
#pragma unroll
        for (int nt = 0; nt < 16; ++nt) {
            ushort4 o;
            o.x = f2b(acc[nt][0] * dv);
            o.y = f2b(acc[nt][1] * dv);
            o.z = f2b(acc[nt][2] * dv);
            o.w = f2b(acc[nt][3] * dv);
            *(ushort4*)&C[base + nt * 16] = o;
        }
    }
}

// ---------------- Fused layer-3 aggregation + mean-pool partials ----------------
__global__ __launch_bounds__(512) void k_agg_pool(
    const ushort* __restrict__ g, const int* __restrict__ rowptr,
    const int* __restrict__ colv, const float* __restrict__ dinv,
    const float* __restrict__ bias, const int* __restrict__ batch,
    float* __restrict__ pooled) {
    __shared__ float srow[8][256];
    __shared__ int wbid[8];
    int wid = threadIdx.x >> 6, lane = threadIdx.x & 63;
    int node = blockIdx.x * 8 + wid;
    bool ok = node < N_NODES;
    int nd = ok ? node : N_NODES - 1;
    int half = lane >> 5;
    int l32 = lane & 31;
    int c8 = l32 * 8;
    float acc[8];
    if (half == 0) {
        u16x8 v = *(const u16x8*)&g[(size_t)nd * HDIM + c8];
#pragma unroll
        for (int j = 0; j < 8; ++j) acc[j] = b2f(v[j]);
    } else {
#pragma unroll
        for (int j = 0; j < 8; ++j) acc[j] = 0.f;
    }
    int s = rowptr[nd], e = rowptr[nd + 1];
    int i = s;
    for (; i + 8 <= e; i += 8) {
        int base = i + half * 4;
        int n0 = colv[base + 0];
        int n1 = colv[base + 1];
        int n2 = colv[base + 2];
        int n3 = colv[base + 3];
        u16x8 v0 = *(const u16x8*)&g[(size_t)n0 * HDIM + c8];
        u16x8 v1 = *(const u16x8*)&g[(size_t)n1 * HDIM + c8];
        u16x8 v2 = *(const u16x8*)&g[(size_t)n2 * HDIM + c8];
        u16x8 v3 = *(const u16x8*)&g[(size_t)n3 * HDIM + c8];
#pragma unroll
        for (int j = 0; j < 8; ++j)
            acc[j] += (b2f(v0[j]) + b2f(v1[j])) + (b2f(v2[j]) + b2f(v3[j]));
    }
    if (i + 4 <= e) {
        int base = i + half * 2;
        int n0 = colv[base + 0];
        int n1 = colv[base + 1];
        u16x8 v0 = *(const u16x8*)&g[(size_t)n0 * HDIM + c8];
        u16x8 v1 = *(const u16x8*)&g[(size_t)n1 * HDIM + c8];
#pragma unroll
        for (int j = 0; j < 8; ++j) acc[j] += b2f(v0[j]) + b2f(v1[j]);
        i += 4;
    }
    if (i + 2 <= e) {
        int n = colv[i + half];
        u16x8 v = *(const u16x8*)&g[(size_t)n * HDIM + c8];
#pragma unroll
        for (int j = 0; j < 8; ++j) acc[j] += b2f(v[j]);
        i += 2;
    }
    if (i < e && half == 0) {
        int n = colv[i];
        u16x8 v = *(const u16x8*)&g[(size_t)n * HDIM + c8];
#pragma unroll
        for (int j = 0; j < 8; ++j) acc[j] += b2f(v[j]);
    }
#pragma unroll
    for (int j = 0; j < 8; ++j) acc[j] += __shfl_xor(acc[j], 32);
    if (half == 0) {
        float dv = dinv[nd];
        float4 bl = *(const float4*)&bias[c8];
        float4 bh = *(const float4*)&bias[c8 + 4];
        float bj[8] = {bl.x, bl.y, bl.z, bl.w, bh.x, bh.y, bh.z, bh.w};
#pragma unroll
        for (int j = 0; j < 8; ++j) {
            float v = fmaxf(fmaf(acc[j], dv, bj[j]), 0.f);
            srow[wid][c8 + j] = ok ? v : 0.f;
        }
        if (l32 == 0) wbid[wid] = batch[nd];
    }
    __syncthreads();
    if (threadIdx.x < 256) {
        int j = threadIdx.x;
        float run = srow[0][j];
        int cur = wbid[0];
        for (int w = 1; w < 8; ++w) {
            int b = wbid[w];
            if (b != cur) {
                atomicAdd(&pooled[cur * HDIM + j], run);
                run = 0.f;
                cur = b;
            }
            run += srow[w][j];
        }
        atomicAdd(&pooled[cur * HDIM + j], run);
    }
}

__global__ __launch_bounds__(128) void k_mlp(const float* __restrict__ pooled,
                                             const int* __restrict__ startb,
                                             const float* __restrict__ svm,
                                             const float* __restrict__ Wf1,
                                             const float* __restrict__ bf1,
                                             const float* __restrict__ Wf2,
                                             const float* __restrict__ bf2,
                                             float* __restrict__ out) {
    __shared__ float fl[257];
    __shared__ float hl[128];
    int b = blockIdx.x;
    int j = threadIdx.x;
    float cntb = fmaxf((float)(startb[b + 1] - startb[b]), 1.0f);
    for (int k = j; k < 256; k += 128) fl[k] = pooled[b * HDIM + k] / cntb;
    if (j == 0) fl[256] = svm[b];
    __syncthreads();
    float acc = bf1[j];
    for (int k = 0; k < 257; ++k) acc = fmaf(fl[k], Wf1[k * 128 + j], acc);
    hl[j] = fmaxf(acc, 0.f);
    __syncthreads();
    if (j < 6) {
        float o = bf2[j];
        for (int k = 0; k < 128; ++k) o = fmaf(hl[k], Wf2[k * 6 + j], o);
        out[b * 6 + j] = o;
    }
}

static inline size_t al256(size_t x) { return (x + 255) & ~(size_t)255; }

extern "C" void kernel_launch(void* const* d_in, const int* in_sizes, int n_in,
                              void* d_out, int out_size, void* d_ws, size_t ws_size,
                              hipStream_t stream) {
    const float* x    = (const float*)d_in[0];
    const int*   ei   = (const int*)d_in[1];
    const int*   batch= (const int*)d_in[2];
    const float* svm  = (const float*)d_in[3];
    const float* W1   = (const float*)d_in[4];
    const float* b1   = (const float*)d_in[5];
    const float* W2   = (const float*)d_in[6];
    const float* b2   = (const float*)d_in[7];
    const float* W3   = (const float*)d_in[8];
    const float* b3   = (const float*)d_in[9];
    const float* Wf1  = (const float*)d_in[10];
    const float* bf1  = (const float*)d_in[11];
    const float* Wf2  = (const float*)d_in[12];
    const float* bf2  = (const float*)d_in[13];
    float* out = (float*)d_out;

    char* w = (char*)d_ws;
    int*    cnt    = (int*)w;    w += al256((size_t)N_NODES * 4);
    int*    rowptr = (int*)w;    w += al256((size_t)(N_NODES + 1) * 4);
    int*    slot   = (int*)w;    w += al256((size_t)N_EDGES * 4);
    int*    colv   = (int*)w;    w += al256((size_t)N_EDGES * 4);
    float*  dinv   = (float*)w;  w += al256((size_t)N_NODES * 4);
    float*  xd     = (float*)w;  w += al256((size_t)N_NODES * 4);
    float2* sd     = (float2*)w; w += al256((size_t)N_NODES * 8);
    int*    startb = (int*)w;    w += al256(65 * 4);
    int*    bsum   = (int*)w;    w += al256((size_t)SCAN_NB * 4);
    float*  pooled = (float*)w;  w += al256((size_t)NGRAPH * HDIM * 4);
    ushort* Wp2    = (ushort*)w; w += al256((size_t)8 * 16 * 64 * 8 * 2);
    ushort* Wp3    = (ushort*)w; w += al256((size_t)8 * 16 * 64 * 8 * 2);
    ushort* bigA   = (ushort*)w; w += al256((size_t)N_NODES * HDIM * 2);
    ushort* bigB   = (ushort*)w; w += al256((size_t)N_NODES * HDIM * 2);

    const int nblkW = (N_NODES + 3) / 4;
    const int nblkS = (N_NODES + 15) / 16;
    const int nblkF = (N_NODES + FB - 1) / FB;
    const int nblkP = (N_NODES + 7) / 8;

    // CSR build
    hipMemsetAsync(cnt, 0, (size_t)N_NODES * 4, stream);
    k_count<<<(N_EDGES / 16 + 255) / 256, 256, 0, stream>>>(ei, cnt, slot);
    k_scan1<<<SCAN_NB, SCAN_BLK, 0, stream>>>(cnt, rowptr, bsum);
    k_scan2b<<<1, 128, 0, stream>>>(bsum, batch, startb, pooled);
    k_dinv_pack<<<NBLK_DINV + 64, 256, 0, stream>>>(cnt, x, bsum, dinv, xd, rowptr,
                                                    W2, Wp2, W3, Wp3);
    k_fill<<<(N_EDGES / 8 + 255) / 256, 256, 0, stream>>>(ei, rowptr, slot, colv);

    // layer 1 scalar agg -> (s, dinv) pairs (16 lanes/node)
    k_s<<<nblkS, 256, 0, stream>>>(rowptr, colv, xd, dinv, sd);

    // layer 2 aggregation (rank-1, scalar gather) -> M (bigA)
    k_aggM<<<nblkW, 256, 0, stream>>>(rowptr, colv, sd, W1, b1, bigA);

    // fused gemm2+gemm3 (h2 in LDS) -> g3 (bigB)
    k_g23<<<nblkF, 256, 0, stream>>>(bigA, Wp2, b2, Wp3, dinv, bigB);

    // fused layer-3 aggregation + mean-pool partial sums
    k_agg_pool<<<nblkP, 512, 0, stream>>>(bigB, rowptr, colv, dinv, b3, batch, pooled);

    // head
    k_mlp<<<NGRAPH, 128, 0, stream>>>(pooled, startb, svm, Wf1, bf1, Wf2, bf2, out);
}